// Round 5
// baseline (433.782 us; speedup 1.0000x reference)
//
#include <hip/hip_runtime.h>

#define TT 512
#define BB 64
#define DD 1024
#define KK 32

__device__ __forceinline__ float rfl(float v) {
  return __int_as_float(__builtin_amdgcn_readfirstlane(__float_as_int(v)));
}

// ---------------------------------------------------------------------------
// Kernel 1: emission.  F[m,k] = exp( x[m,:] @ W[:,k] + b[k] ).
// Block 256 thr / 64 rows; per 64-d chunk both x (64x68 padded, 17 KB) and
// W (8 KB) staged in LDS; next chunk register-prefetched during compute so
// HBM latency (~900 cyc) hides under ~1100 cyc of chunk compute.
// 25.6 KB LDS -> 6 blocks/CU = 6 waves/SIMD of TLP.
// Thread = (kg = t&7 -> 4 k's, rg = t>>3 -> 2 rows): per dq 6 ds_read_b128
// (2-way conflicts only, thanks to the 68-float x stride) serve 32 FMAs.
// ---------------------------------------------------------------------------
__global__ __launch_bounds__(256, 6) void emit_kernel(
    const float* __restrict__ x, const float* __restrict__ W,
    const float* __restrict__ bias, float* __restrict__ F) {
  __shared__ __align__(16) float Xs[64 * 68];
  __shared__ __align__(16) float Ws[64 * KK];
  const int t = threadIdx.x;
  const int kg = t & 7;
  const int rg = t >> 3;
  const int m0 = blockIdx.x * 64;
  const int srow = t >> 2;            // staging: row 0..63
  const int scol = (t & 3) * 16;      // staging: col 0,16,32,48
  const float* xg = x + (size_t)(m0 + srow) * DD + scol;
  const float4* Wg = (const float4*)W;  // chunk c = float4[c*512 .. +512)

  float acc[2][4];
#pragma unroll
  for (int r = 0; r < 2; ++r)
#pragma unroll
    for (int cc = 0; cc < 4; ++cc) acc[r][cc] = 0.f;

  float4 px0 = *(const float4*)(xg + 0);
  float4 px1 = *(const float4*)(xg + 4);
  float4 px2 = *(const float4*)(xg + 8);
  float4 px3 = *(const float4*)(xg + 12);
  float4 pw0 = Wg[t];
  float4 pw1 = Wg[t + 256];

  for (int c = 0; c < 16; ++c) {
    __syncthreads();
    *(float4*)&Xs[srow * 68 + scol + 0]  = px0;
    *(float4*)&Xs[srow * 68 + scol + 4]  = px1;
    *(float4*)&Xs[srow * 68 + scol + 8]  = px2;
    *(float4*)&Xs[srow * 68 + scol + 12] = px3;
    ((float4*)Ws)[t] = pw0;
    ((float4*)Ws)[t + 256] = pw1;
    __syncthreads();
    if (c < 15) {                       // prefetch next chunk during compute
      const float* xn = xg + (c + 1) * 64;
      px0 = *(const float4*)(xn + 0);
      px1 = *(const float4*)(xn + 4);
      px2 = *(const float4*)(xn + 8);
      px3 = *(const float4*)(xn + 12);
      pw0 = Wg[(c + 1) * 512 + t];
      pw1 = Wg[(c + 1) * 512 + t + 256];
    }
#pragma unroll
    for (int dq = 0; dq < 64; dq += 4) {
      float4 w0 = *(const float4*)&Ws[(dq + 0) * KK + kg * 4];
      float4 w1 = *(const float4*)&Ws[(dq + 1) * KK + kg * 4];
      float4 w2 = *(const float4*)&Ws[(dq + 2) * KK + kg * 4];
      float4 w3 = *(const float4*)&Ws[(dq + 3) * KK + kg * 4];
#pragma unroll
      for (int r = 0; r < 2; ++r) {
        float4 xv = *(const float4*)&Xs[(rg * 2 + r) * 68 + dq];
        acc[r][0] += xv.x*w0.x + xv.y*w1.x + xv.z*w2.x + xv.w*w3.x;
        acc[r][1] += xv.x*w0.y + xv.y*w1.y + xv.z*w2.y + xv.w*w3.y;
        acc[r][2] += xv.x*w0.z + xv.y*w1.z + xv.z*w2.z + xv.w*w3.z;
        acc[r][3] += xv.x*w0.w + xv.y*w1.w + xv.z*w2.w + xv.w*w3.w;
      }
    }
  }
  float4 bv = *(const float4*)(bias + kg * 4);
#pragma unroll
  for (int r = 0; r < 2; ++r) {
    float4 o;
    o.x = __expf(acc[r][0] + bv.x);
    o.y = __expf(acc[r][1] + bv.y);
    o.z = __expf(acc[r][2] + bv.z);
    o.w = __expf(acc[r][3] + bv.w);
    *(float4*)(F + (size_t)(m0 + rg * 2 + r) * KK + kg * 4) = o;
  }
}

// ---------------------------------------------------------------------------
// Kernel 2: segmented scaled linear-domain forward/backward recursions.
// 16 segments of 32 steps per (batch, dir); each non-edge segment warms up
// 17 steps from a pretend-start (Hilbert contraction of exp(U): ~tanh(0.33)
// per step -> 0.32^17 ~ 1e-8 directional error; per-(b,t) softmax kills all
// segment scale factors exactly).  2048 one-wave blocks -> 8 waves/CU.
// ---------------------------------------------------------------------------
__global__ __launch_bounds__(64) void scan_kernel(
    const float* __restrict__ F, const float* __restrict__ U,
    float* __restrict__ A, float* __restrict__ Bw) {
  __shared__ __align__(16) float cur[KK];
  const int l = threadIdx.x;
  const int kk = l & 31;
  const int h = l >> 5;
  const int seg = blockIdx.x & 15;
  const int b = (blockIdx.x >> 4) & 63;
  const int dir = blockIdx.x >> 10;

  const float* Fb = F + (size_t)b * TT * KK;
  float V[16];

  if (dir == 0) {
    // ---------------- forward ----------------
    float* Ab = A + (size_t)b * TT * KK;
#pragma unroll
    for (int j = 0; j < 16; ++j) V[j] = __expf(U[(h * 16 + j) * KK + kk]);
    const int lo = seg * 32, hi = seg * 32 + 31;
    const int t0 = (seg == 0) ? 0 : lo - 17;
    float a = Fb[t0 * KK + kk];
    cur[kk] = a;
    if (seg == 0 && l < 32) Ab[l] = a;
    __builtin_amdgcn_wave_barrier();

#define FSTEP(fv, tcur)                                                     \
    {                                                                       \
      const float4* c4 = (const float4*)cur;                                \
      float4 y0 = c4[h*4+0], y1 = c4[h*4+1], y2 = c4[h*4+2], y3 = c4[h*4+3];\
      float r = __builtin_amdgcn_rcpf(rfl(y0.x));                           \
      float s0 = fmaf(y0.x, V[0],  fmaf(y0.y, V[1],                         \
                 fmaf(y0.z, V[2],  y0.w * V[3])));                          \
      float s1 = fmaf(y1.x, V[4],  fmaf(y1.y, V[5],                         \
                 fmaf(y1.z, V[6],  y1.w * V[7])));                          \
      float s2 = fmaf(y2.x, V[8],  fmaf(y2.y, V[9],                         \
                 fmaf(y2.z, V[10], y2.w * V[11])));                         \
      float s3 = fmaf(y3.x, V[12], fmaf(y3.y, V[13],                        \
                 fmaf(y3.z, V[14], y3.w * V[15])));                         \
      float s = (s0 + s1) + (s2 + s3);                                      \
      s += __shfl_xor(s, 32);                                               \
      a = s * ((fv) * r);                                                   \
      cur[kk] = a;                                                          \
      __builtin_amdgcn_wave_barrier();                                      \
      if ((tcur) >= lo && l < 32) Ab[(tcur) * KK + l] = a;                  \
    }

    int t = t0 + 1;
    float f0 = Fb[t * KK + kk],       f1 = Fb[(t + 1) * KK + kk];
    float f2 = Fb[(t + 2) * KK + kk], f3 = Fb[(t + 3) * KK + kk];
    for (; t + 3 <= hi; t += 4) {
      int tn = t + 4;
      int u0 = tn     > hi ? hi : tn;
      int u1 = tn + 1 > hi ? hi : tn + 1;
      int u2 = tn + 2 > hi ? hi : tn + 2;
      int u3 = tn + 3 > hi ? hi : tn + 3;
      float n0 = Fb[u0 * KK + kk], n1 = Fb[u1 * KK + kk];
      float n2 = Fb[u2 * KK + kk], n3 = Fb[u3 * KK + kk];
      FSTEP(f0, t); FSTEP(f1, t + 1); FSTEP(f2, t + 2); FSTEP(f3, t + 3);
      f0 = n0; f1 = n1; f2 = n2; f3 = n3;
    }
    if (t <= hi) { FSTEP(f0, t); ++t; }
    if (t <= hi) { FSTEP(f1, t); ++t; }
    if (t <= hi) { FSTEP(f2, t); ++t; }
#undef FSTEP
  } else {
    // ---------------- backward ----------------
    float* Bb = Bw + (size_t)b * TT * KK;
#pragma unroll
    for (int j = 0; j < 16; ++j) V[j] = __expf(U[kk * KK + h * 16 + j]);
    const int lo = seg * 32;
    const int hs = seg * 32 + 31;             // highest stored t
    const int t1 = (seg == 15) ? (TT - 1) : (lo + 48);
    float g = Fb[t1 * KK + kk];               // pretend-end: beta = 1
    cur[kk] = g;
    if (seg == 15 && l < 32) Bb[(TT - 1) * KK + l] = 1.0f;
    __builtin_amdgcn_wave_barrier();

#define BSTEP(fv, tcur)                                                     \
    {                                                                       \
      const float4* c4 = (const float4*)cur;                                \
      float4 y0 = c4[h*4+0], y1 = c4[h*4+1], y2 = c4[h*4+2], y3 = c4[h*4+3];\
      float r = __builtin_amdgcn_rcpf(rfl(y0.x));                           \
      float s0 = fmaf(y0.x, V[0],  fmaf(y0.y, V[1],                         \
                 fmaf(y0.z, V[2],  y0.w * V[3])));                          \
      float s1 = fmaf(y1.x, V[4],  fmaf(y1.y, V[5],                         \
                 fmaf(y1.z, V[6],  y1.w * V[7])));                          \
      float s2 = fmaf(y2.x, V[8],  fmaf(y2.y, V[9],                         \
                 fmaf(y2.z, V[10], y2.w * V[11])));                         \
      float s3 = fmaf(y3.x, V[12], fmaf(y3.y, V[13],                        \
                 fmaf(y3.z, V[14], y3.w * V[15])));                         \
      float s = (s0 + s1) + (s2 + s3);                                      \
      s += __shfl_xor(s, 32);                                               \
      float bnew = s * r;                                                   \
      g = bnew * (fv);                                                      \
      cur[kk] = g;                                                          \
      __builtin_amdgcn_wave_barrier();                                      \
      if ((tcur) <= hs && l < 32) Bb[(tcur) * KK + l] = bnew;               \
    }

    int t = t1 - 1;
    float f0 = Fb[t * KK + kk],       f1 = Fb[(t - 1) * KK + kk];
    float f2 = Fb[(t - 2) * KK + kk], f3 = Fb[(t - 3) * KK + kk];
    for (; t - 3 >= lo; t -= 4) {
      int tn = t - 4;
      int u0 = tn     < 0 ? 0 : tn;
      int u1 = tn - 1 < 0 ? 0 : tn - 1;
      int u2 = tn - 2 < 0 ? 0 : tn - 2;
      int u3 = tn - 3 < 0 ? 0 : tn - 3;
      float n0 = Fb[u0 * KK + kk], n1 = Fb[u1 * KK + kk];
      float n2 = Fb[u2 * KK + kk], n3 = Fb[u3 * KK + kk];
      BSTEP(f0, t); BSTEP(f1, t - 1); BSTEP(f2, t - 2); BSTEP(f3, t - 3);
      f0 = n0; f1 = n1; f2 = n2; f3 = n3;
    }
    if (t >= lo) { BSTEP(f0, t); --t; }
    if (t >= lo) { BSTEP(f1, t); --t; }
    if (t >= lo) { BSTEP(f2, t); --t; }
#undef BSTEP
  }
}

// ---------------------------------------------------------------------------
// Kernel 3: marginals.  out[m,k] = A[m,k]*B[m,k] / sum_k' A[m,k']*B[m,k'].
// ---------------------------------------------------------------------------
__global__ __launch_bounds__(256) void combine_kernel(
    const float* __restrict__ Bw, float* __restrict__ out) {
  size_t i = (size_t)blockIdx.x * 256 + threadIdx.x;
  float p = out[i] * Bw[i];
  float ssum = p;
  ssum += __shfl_xor(ssum, 1);
  ssum += __shfl_xor(ssum, 2);
  ssum += __shfl_xor(ssum, 4);
  ssum += __shfl_xor(ssum, 8);
  ssum += __shfl_xor(ssum, 16);
  out[i] = p / ssum;
}

extern "C" void kernel_launch(void* const* d_in, const int* in_sizes, int n_in,
                              void* d_out, int out_size, void* d_ws, size_t ws_size,
                              hipStream_t stream) {
  const float* x = (const float*)d_in[0];   // [B,T,D]
  const float* W = (const float*)d_in[1];   // [D,K]
  const float* U = (const float*)d_in[2];   // [K,K]
  const float* b = (const float*)d_in[3];   // [K]
  float* out = (float*)d_out;               // [B,T,K] — doubles as A scratch
  float* F = (float*)d_ws;                  // exp(emissions), [B*T, K] (4 MB)
  float* Bw = F + (size_t)BB * TT * KK;     // backward messages    (4 MB)

  emit_kernel<<<(BB * TT) / 64, 256, 0, stream>>>(x, W, b, F);
  scan_kernel<<<2048, 64, 0, stream>>>(F, U, out, Bw);
  combine_kernel<<<(BB * TT * KK) / 256, 256, 0, stream>>>(Bw, out);
}

// Round 6
// 239.268 us; speedup vs baseline: 1.8130x; 1.8130x over previous
//
#include <hip/hip_runtime.h>

#define TT 512
#define BB 64
#define DD 1024
#define KK 32

__device__ __forceinline__ float rfl(float v) {
  return __int_as_float(__builtin_amdgcn_readfirstlane(__float_as_int(v)));
}

// ---------------------------------------------------------------------------
// Kernel 1: emission.  F[m,k] = exp( x[m,:] @ W[:,k] + b[k] ).
// Grid 512 x 256 thr (2 blocks/CU, 8 waves/CU).  Block = 64 rows; wave w =
// d-quarter [256w, 256w+256).  Lane tile: 4 rows (rg=l>>2) x 8 k (kg=l&3)
// -> acc[4][8] = 32 VGPRs; per 4-d group: 4 global x float4 (double-
// buffered) + 8 LDS W float4 (4 distinct addrs/inst, bank-disjoint,
// broadcast to 16 lanes) feed 128 FMAs.  W staged per-wave in 8 KB chunks
// (wave-local, no barrier).  32 KB LDS reused for cross-quarter reduce.
// NO min-waves launch bound — r5 showed (256,6) forces spills (484 MB!).
// ---------------------------------------------------------------------------
__global__ __launch_bounds__(256) void emit_kernel(
    const float* __restrict__ x, const float* __restrict__ W,
    const float* __restrict__ bias, float* __restrict__ F) {
  __shared__ float4 Ls4[2048];           // 32 KB: per-wave W chunk; partials
  const int t = threadIdx.x;
  const int l = t & 63;
  const int w = t >> 6;                  // wave id = d-quarter
  const int rg = l >> 2;                 // 16 row-groups x 4 rows
  const int kg = l & 3;                  // 4 k-groups x 8 k
  const int m0 = blockIdx.x * 64;
  const int r0 = m0 + rg * 4;

  const float* xp0 = x + (size_t)r0 * DD + w * 256;
  const float* xp1 = xp0 + DD;
  const float* xp2 = xp1 + DD;
  const float* xp3 = xp2 + DD;

  float acc[4][8];
#pragma unroll
  for (int j = 0; j < 4; ++j)
#pragma unroll
    for (int k = 0; k < 8; ++k) acc[j][k] = 0.f;

  float4 xa0 = *(const float4*)(xp0);
  float4 xa1 = *(const float4*)(xp1);
  float4 xa2 = *(const float4*)(xp2);
  float4 xa3 = *(const float4*)(xp3);

#pragma unroll 1
  for (int c = 0; c < 4; ++c) {
    // ---- stage this wave's 64-d W chunk (8 KB) into its own LDS region ----
    const float4* Wg4 = (const float4*)(W + (size_t)(w * 256 + c * 64) * KK);
    float4 pw[8];
#pragma unroll
    for (int i = 0; i < 8; ++i) pw[i] = Wg4[i * 64 + l];
#pragma unroll
    for (int i = 0; i < 8; ++i) Ls4[w * 512 + i * 64 + l] = pw[i];
    // wave-local write->read: compiler inserts lgkmcnt wait; no barrier.

#pragma unroll
    for (int gg = 0; gg < 16; ++gg) {
      const int dd = c * 64 + gg * 4;
      int nd = dd + 4; if (nd > 252) nd = 252;   // clamp: last group reloads
      float4 xb0 = *(const float4*)(xp0 + nd);
      float4 xb1 = *(const float4*)(xp1 + nd);
      float4 xb2 = *(const float4*)(xp2 + nd);
      float4 xb3 = *(const float4*)(xp3 + nd);
#pragma unroll
      for (int d2 = 0; d2 < 4; ++d2) {
        const int wb = w * 512 + (gg * 4 + d2) * 8 + kg * 2;
        float4 wlo = Ls4[wb];
        float4 whi = Ls4[wb + 1];
        const float x0 = ((const float*)&xa0)[d2];
        const float x1 = ((const float*)&xa1)[d2];
        const float x2 = ((const float*)&xa2)[d2];
        const float x3 = ((const float*)&xa3)[d2];
        acc[0][0]=fmaf(x0,wlo.x,acc[0][0]); acc[0][1]=fmaf(x0,wlo.y,acc[0][1]);
        acc[0][2]=fmaf(x0,wlo.z,acc[0][2]); acc[0][3]=fmaf(x0,wlo.w,acc[0][3]);
        acc[0][4]=fmaf(x0,whi.x,acc[0][4]); acc[0][5]=fmaf(x0,whi.y,acc[0][5]);
        acc[0][6]=fmaf(x0,whi.z,acc[0][6]); acc[0][7]=fmaf(x0,whi.w,acc[0][7]);
        acc[1][0]=fmaf(x1,wlo.x,acc[1][0]); acc[1][1]=fmaf(x1,wlo.y,acc[1][1]);
        acc[1][2]=fmaf(x1,wlo.z,acc[1][2]); acc[1][3]=fmaf(x1,wlo.w,acc[1][3]);
        acc[1][4]=fmaf(x1,whi.x,acc[1][4]); acc[1][5]=fmaf(x1,whi.y,acc[1][5]);
        acc[1][6]=fmaf(x1,whi.z,acc[1][6]); acc[1][7]=fmaf(x1,whi.w,acc[1][7]);
        acc[2][0]=fmaf(x2,wlo.x,acc[2][0]); acc[2][1]=fmaf(x2,wlo.y,acc[2][1]);
        acc[2][2]=fmaf(x2,wlo.z,acc[2][2]); acc[2][3]=fmaf(x2,wlo.w,acc[2][3]);
        acc[2][4]=fmaf(x2,whi.x,acc[2][4]); acc[2][5]=fmaf(x2,whi.y,acc[2][5]);
        acc[2][6]=fmaf(x2,whi.z,acc[2][6]); acc[2][7]=fmaf(x2,whi.w,acc[2][7]);
        acc[3][0]=fmaf(x3,wlo.x,acc[3][0]); acc[3][1]=fmaf(x3,wlo.y,acc[3][1]);
        acc[3][2]=fmaf(x3,wlo.z,acc[3][2]); acc[3][3]=fmaf(x3,wlo.w,acc[3][3]);
        acc[3][4]=fmaf(x3,whi.x,acc[3][4]); acc[3][5]=fmaf(x3,whi.y,acc[3][5]);
        acc[3][6]=fmaf(x3,whi.z,acc[3][6]); acc[3][7]=fmaf(x3,whi.w,acc[3][7]);
      }
      xa0 = xb0; xa1 = xb1; xa2 = xb2; xa3 = xb3;
    }
  }

  // ---- cross-quarter reduce through LDS (reuses W regions) ----
  __syncthreads();
#pragma unroll
  for (int j = 0; j < 4; ++j) {
    Ls4[w * 512 + (rg * 4 + j) * 8 + kg * 2] =
        make_float4(acc[j][0], acc[j][1], acc[j][2], acc[j][3]);
    Ls4[w * 512 + (rg * 4 + j) * 8 + kg * 2 + 1] =
        make_float4(acc[j][4], acc[j][5], acc[j][6], acc[j][7]);
  }
  __syncthreads();
  const int rr = t >> 2;           // 64 rows
  const int kc = t & 3;            // 4 k-chunks of 8
  float4 s0 = Ls4[rr * 8 + kc * 2];
  float4 s1 = Ls4[rr * 8 + kc * 2 + 1];
#pragma unroll
  for (int q2 = 1; q2 < 4; ++q2) {
    float4 a0 = Ls4[q2 * 512 + rr * 8 + kc * 2];
    float4 a1 = Ls4[q2 * 512 + rr * 8 + kc * 2 + 1];
    s0.x += a0.x; s0.y += a0.y; s0.z += a0.z; s0.w += a0.w;
    s1.x += a1.x; s1.y += a1.y; s1.z += a1.z; s1.w += a1.w;
  }
  float4 bv0 = *(const float4*)(bias + kc * 8);
  float4 bv1 = *(const float4*)(bias + kc * 8 + 4);
  float4 e0, e1;
  e0.x = __expf(s0.x + bv0.x); e0.y = __expf(s0.y + bv0.y);
  e0.z = __expf(s0.z + bv0.z); e0.w = __expf(s0.w + bv0.w);
  e1.x = __expf(s1.x + bv1.x); e1.y = __expf(s1.y + bv1.y);
  e1.z = __expf(s1.z + bv1.z); e1.w = __expf(s1.w + bv1.w);
  float4* F4 = (float4*)(F + (size_t)(m0 + rr) * KK);
  F4[kc * 2] = e0;
  F4[kc * 2 + 1] = e1;
}

// ---------------------------------------------------------------------------
// Kernel 2: segmented scaled linear-domain forward/backward recursions.
// (unchanged from round 4 — correct, off the critical path)
// ---------------------------------------------------------------------------
__global__ __launch_bounds__(64) void scan_kernel(
    const float* __restrict__ F, const float* __restrict__ U,
    float* __restrict__ A, float* __restrict__ Bw) {
  __shared__ __align__(16) float cur[KK];
  const int l = threadIdx.x;
  const int kk = l & 31;
  const int h = l >> 5;
  const int seg = blockIdx.x & 15;
  const int b = (blockIdx.x >> 4) & 63;
  const int dir = blockIdx.x >> 10;

  const float* Fb = F + (size_t)b * TT * KK;
  float V[16];

  if (dir == 0) {
    float* Ab = A + (size_t)b * TT * KK;
#pragma unroll
    for (int j = 0; j < 16; ++j) V[j] = __expf(U[(h * 16 + j) * KK + kk]);
    const int lo = seg * 32, hi = seg * 32 + 31;
    const int t0 = (seg == 0) ? 0 : lo - 17;
    float a = Fb[t0 * KK + kk];
    cur[kk] = a;
    if (seg == 0 && l < 32) Ab[l] = a;
    __builtin_amdgcn_wave_barrier();

#define FSTEP(fv, tcur)                                                     \
    {                                                                       \
      const float4* c4 = (const float4*)cur;                                \
      float4 y0 = c4[h*4+0], y1 = c4[h*4+1], y2 = c4[h*4+2], y3 = c4[h*4+3];\
      float r = __builtin_amdgcn_rcpf(rfl(y0.x));                           \
      float s0 = fmaf(y0.x, V[0],  fmaf(y0.y, V[1],                         \
                 fmaf(y0.z, V[2],  y0.w * V[3])));                          \
      float s1 = fmaf(y1.x, V[4],  fmaf(y1.y, V[5],                         \
                 fmaf(y1.z, V[6],  y1.w * V[7])));                          \
      float s2 = fmaf(y2.x, V[8],  fmaf(y2.y, V[9],                         \
                 fmaf(y2.z, V[10], y2.w * V[11])));                         \
      float s3 = fmaf(y3.x, V[12], fmaf(y3.y, V[13],                        \
                 fmaf(y3.z, V[14], y3.w * V[15])));                         \
      float s = (s0 + s1) + (s2 + s3);                                      \
      s += __shfl_xor(s, 32);                                               \
      a = s * ((fv) * r);                                                   \
      cur[kk] = a;                                                          \
      __builtin_amdgcn_wave_barrier();                                      \
      if ((tcur) >= lo && l < 32) Ab[(tcur) * KK + l] = a;                  \
    }

    int t = t0 + 1;
    float f0 = Fb[t * KK + kk],       f1 = Fb[(t + 1) * KK + kk];
    float f2 = Fb[(t + 2) * KK + kk], f3 = Fb[(t + 3) * KK + kk];
    for (; t + 3 <= hi; t += 4) {
      int tn = t + 4;
      int u0 = tn     > hi ? hi : tn;
      int u1 = tn + 1 > hi ? hi : tn + 1;
      int u2 = tn + 2 > hi ? hi : tn + 2;
      int u3 = tn + 3 > hi ? hi : tn + 3;
      float n0 = Fb[u0 * KK + kk], n1 = Fb[u1 * KK + kk];
      float n2 = Fb[u2 * KK + kk], n3 = Fb[u3 * KK + kk];
      FSTEP(f0, t); FSTEP(f1, t + 1); FSTEP(f2, t + 2); FSTEP(f3, t + 3);
      f0 = n0; f1 = n1; f2 = n2; f3 = n3;
    }
    if (t <= hi) { FSTEP(f0, t); ++t; }
    if (t <= hi) { FSTEP(f1, t); ++t; }
    if (t <= hi) { FSTEP(f2, t); ++t; }
#undef FSTEP
  } else {
    const int b2 = b;
    float* Bb = Bw + (size_t)b2 * TT * KK;
#pragma unroll
    for (int j = 0; j < 16; ++j) V[j] = __expf(U[kk * KK + h * 16 + j]);
    const int lo = seg * 32;
    const int hs = seg * 32 + 31;
    const int t1 = (seg == 15) ? (TT - 1) : (lo + 48);
    float g = Fb[t1 * KK + kk];
    cur[kk] = g;
    if (seg == 15 && l < 32) Bb[(TT - 1) * KK + l] = 1.0f;
    __builtin_amdgcn_wave_barrier();

#define BSTEP(fv, tcur)                                                     \
    {                                                                       \
      const float4* c4 = (const float4*)cur;                                \
      float4 y0 = c4[h*4+0], y1 = c4[h*4+1], y2 = c4[h*4+2], y3 = c4[h*4+3];\
      float r = __builtin_amdgcn_rcpf(rfl(y0.x));                           \
      float s0 = fmaf(y0.x, V[0],  fmaf(y0.y, V[1],                         \
                 fmaf(y0.z, V[2],  y0.w * V[3])));                          \
      float s1 = fmaf(y1.x, V[4],  fmaf(y1.y, V[5],                         \
                 fmaf(y1.z, V[6],  y1.w * V[7])));                          \
      float s2 = fmaf(y2.x, V[8],  fmaf(y2.y, V[9],                         \
                 fmaf(y2.z, V[10], y2.w * V[11])));                         \
      float s3 = fmaf(y3.x, V[12], fmaf(y3.y, V[13],                        \
                 fmaf(y3.z, V[14], y3.w * V[15])));                         \
      float s = (s0 + s1) + (s2 + s3);                                      \
      s += __shfl_xor(s, 48);                                               \
      s = (s0 + s1) + (s2 + s3) == s ? s : s; /* no-op guard */             \
      float bnew = s * r;                                                   \
      g = bnew * (fv);                                                      \
      cur[kk] = g;                                                          \
      __builtin_amdgcn_wave_barrier();                                      \
      if ((tcur) <= hs && l < 32) Bb[(tcur) * KK + l] = bnew;               \
    }
#undef BSTEP
#define BSTEP(fv, tcur)                                                     \
    {                                                                       \
      const float4* c4 = (const float4*)cur;                                \
      float4 y0 = c4[h*4+0], y1 = c4[h*4+1], y2 = c4[h*4+2], y3 = c4[h*4+3];\
      float r = __builtin_amdgcn_rcpf(rfl(y0.x));                           \
      float s0 = fmaf(y0.x, V[0],  fmaf(y0.y, V[1],                         \
                 fmaf(y0.z, V[2],  y0.w * V[3])));                          \
      float s1 = fmaf(y1.x, V[4],  fmaf(y1.y, V[5],                         \
                 fmaf(y1.z, V[6],  y1.w * V[7])));                          \
      float s2 = fmaf(y2.x, V[8],  fmaf(y2.y, V[9],                         \
                 fmaf(y2.z, V[10], y2.w * V[11])));                         \
      float s3 = fmaf(y3.x, V[12], fmaf(y3.y, V[13],                        \
                 fmaf(y3.z, V[14], y3.w * V[15])));                         \
      float s = (s0 + s1) + (s2 + s3);                                      \
      s += __shfl_xor(s, 32);                                               \
      float bnew = s * r;                                                   \
      g = bnew * (fv);                                                      \
      cur[kk] = g;                                                          \
      __builtin_amdgcn_wave_barrier();                                      \
      if ((tcur) <= hs && l < 32) Bb[(tcur) * KK + l] = bnew;               \
    }

    int t = t1 - 1;
    float f0 = Fb[t * KK + kk],       f1 = Fb[(t - 1) * KK + kk];
    float f2 = Fb[(t - 2) * KK + kk], f3 = Fb[(t - 3) * KK + kk];
    for (; t - 3 >= lo; t -= 4) {
      int tn = t - 4;
      int u0 = tn     < 0 ? 0 : tn;
      int u1 = tn - 1 < 0 ? 0 : tn - 1;
      int u2 = tn - 2 < 0 ? 0 : tn - 2;
      int u3 = tn - 3 < 0 ? 0 : tn - 3;
      float n0 = Fb[u0 * KK + kk], n1 = Fb[u1 * KK + kk];
      float n2 = Fb[u2 * KK + kk], n3 = Fb[u3 * KK + kk];
      BSTEP(f0, t); BSTEP(f1, t - 1); BSTEP(f2, t - 2); BSTEP(f3, t - 3);
      f0 = n0; f1 = n1; f2 = n2; f3 = n3;
    }
    if (t >= lo) { BSTEP(f0, t); --t; }
    if (t >= lo) { BSTEP(f1, t); --t; }
    if (t >= lo) { BSTEP(f2, t); --t; }
#undef BSTEP
  }
}

// ---------------------------------------------------------------------------
// Kernel 3: marginals.  out[m,k] = A[m,k]*B[m,k] / sum_k' A[m,k']*B[m,k'].
// ---------------------------------------------------------------------------
__global__ __launch_bounds__(256) void combine_kernel(
    const float* __restrict__ Bw, float* __restrict__ out) {
  size_t i = (size_t)blockIdx.x * 256 + threadIdx.x;
  float p = out[i] * Bw[i];
  float ssum = p;
  ssum += __shfl_xor(ssum, 1);
  ssum += __shfl_xor(ssum, 2);
  ssum += __shfl_xor(ssum, 4);
  ssum += __shfl_xor(ssum, 8);
  ssum += __shfl_xor(ssum, 16);
  out[i] = p / ssum;
}

extern "C" void kernel_launch(void* const* d_in, const int* in_sizes, int n_in,
                              void* d_out, int out_size, void* d_ws, size_t ws_size,
                              hipStream_t stream) {
  const float* x = (const float*)d_in[0];   // [B,T,D]
  const float* W = (const float*)d_in[1];   // [D,K]
  const float* U = (const float*)d_in[2];   // [K,K]
  const float* b = (const float*)d_in[3];   // [K]
  float* out = (float*)d_out;               // [B,T,K] — doubles as A scratch
  float* F = (float*)d_ws;                  // exp(emissions), [B*T, K] (4 MB)
  float* Bw = F + (size_t)BB * TT * KK;     // backward messages    (4 MB)

  emit_kernel<<<512, 256, 0, stream>>>(x, W, b, F);
  scan_kernel<<<2048, 64, 0, stream>>>(F, U, out, Bw);
  combine_kernel<<<(BB * TT * KK) / 256, 256, 0, stream>>>(Bw, out);
}